// Round 4
// baseline (935.518 us; speedup 1.0000x reference)
//
#include <hip/hip_runtime.h>
#include <stdint.h>

#define HH 8
#define DDIM 512
#define KHEAD 64
#define FFD 64
#define LLEN 512
#define BBATCH 32
#define NTOK 16384  // L*B

typedef unsigned short u16;
typedef __attribute__((ext_vector_type(8))) __bf16 bf16x8;
typedef __attribute__((ext_vector_type(4))) float f32x4;

__device__ __forceinline__ float bf2f(u16 u) {
    union { uint32_t i; float f; } v; v.i = ((uint32_t)u) << 16; return v.f;
}
__device__ __forceinline__ u16 f2bf(float f) {
    union { uint32_t i; float f; } v; v.f = f;
    return (u16)((v.i + 0x7FFFu + ((v.i >> 16) & 1u)) >> 16);
}

__device__ __forceinline__ void gload16(const void* g, void* l) {
    __builtin_amdgcn_global_load_lds(
        (const __attribute__((address_space(1))) void*)g,
        (__attribute__((address_space(3))) void*)l, 16, 0, 0);
}

// fp32 -> bf16 (RNE), 4 elems/thread
__global__ __launch_bounds__(256) void f2bf4(const float* __restrict__ in,
                                             u16* __restrict__ out, int n4) {
    int i = blockIdx.x * 256 + threadIdx.x;
    if (i >= n4) return;
    float4 v = ((const float4*)in)[i];
    ushort4 o; o.x = f2bf(v.x); o.y = f2bf(v.y); o.z = f2bf(v.z); o.w = f2bf(v.w);
    ((ushort4*)out)[i] = o;
}

// W2 [H*512 rows][64] fp32 -> bf16 with row-XOR swizzle (e ^ ((r&7)<<3)),
// so ffn_fused can stage it into LDS as a linear copy and read conflict-free.
__global__ __launch_bounds__(256) void f2bf_w2(const float* __restrict__ in,
                                               u16* __restrict__ out) {
    const int id = blockIdx.x * 256 + threadIdx.x;   // 32768 ids, 8 elems each
    const int r = id >> 3, cg = (id & 7) * 8;
    const float* ip = in + r * 64 + cg;
    const int sw = (r & 7) << 3;
    float4 a = ((const float4*)ip)[0];
    float4 b = ((const float4*)ip)[1];
    ushort4 lo, hi;
    lo.x = f2bf(a.x); lo.y = f2bf(a.y); lo.z = f2bf(a.z); lo.w = f2bf(a.w);
    hi.x = f2bf(b.x); hi.y = f2bf(b.y); hi.z = f2bf(b.z); hi.w = f2bf(b.w);
    u16* op = out + r * 64 + (cg ^ sw);
    ((ushort4*)op)[0] = lo;
    ((ushort4*)op)[1] = hi;
}

enum { M_PLAIN = 0, M_WQK = 1, M_SUBAUX = 2, M_RELU = 3, M_ADDAUX = 4, M_SCALECOL = 5 };

// MFMA batched GEMM, both operands K-contiguous ("B^T form"):
//   C[m,n] = sum_k A[m,k] * B[n,k]   (bf16 in, fp32 acc, bf16 out)
// ZMAP: 0 = h-major (h2=z/nB2, b2=z%nB2); 1 = b-major (h2=z&7, b2=z>>3);
//       2 = grouped 8h x 8b (h2=(z>>3)&7, b2=(z>>6)*8 + (z&7)).
template<int BM, int BN, int MODE, int ZMAP>
__global__ __launch_bounds__(256) void mgemm(
    const u16* __restrict__ A, const u16* __restrict__ B, u16* __restrict__ C,
    int Kd, int lda, int ldb, int ldc,
    long Ash, long Asb, long Bsh, long Bsb, long Csh, long Csb, int nB2,
    const float* __restrict__ bias, int biasN,
    const void* __restrict__ auxp, long auxsh, long auxsb, int auxld)
{
    constexpr int WC = (BN == 128) ? 2 : 1;
    constexpr int WR = 4 / WC;
    constexpr int WTM = BM / WR;
    constexpr int WTN = BN / WC;
    constexpr int MF = WTM / 16;
    constexpr int NF = WTN / 16;
    constexpr int NCA = (BM * 64) / 4096;
    constexpr int NCB = (BN * 64) / 4096;
    __shared__ u16 As[BM * 32];
    __shared__ u16 Bs[BN * 32];

    const int z = blockIdx.z;
    int h2, b2;
    if (ZMAP == 0)      { h2 = z / nB2;      b2 = z % nB2; }
    else if (ZMAP == 1) { h2 = z & 7;        b2 = z >> 3; }
    else                { h2 = (z >> 3) & 7; b2 = ((z >> 6) << 3) | (z & 7); }
    const u16* Ab = A + h2 * Ash + b2 * Asb;
    const u16* Bb = B + h2 * Bsh + b2 * Bsb;
    const int m0 = blockIdx.x * BM, n0 = blockIdx.y * BN;
    const int t = threadIdx.x;
    const int lane = t & 63;
    const int w = t >> 6;
    const int wr = w / WC, wc = w % WC;
    const int tb = t * 16;
    const int wb = (t & 192) * 16;

    f32x4 acc[MF][NF];
    #pragma unroll
    for (int m = 0; m < MF; ++m)
        #pragma unroll
        for (int n = 0; n < NF; ++n)
            #pragma unroll
            for (int i = 0; i < 4; ++i) acc[m][n][i] = 0.f;

    const int ko = (lane >> 4) * 16;

    for (int k0 = 0; k0 < Kd; k0 += 32) {
        #pragma unroll
        for (int c = 0; c < NCA; ++c) {
            const int byte = c * 4096 + tb;
            const int row = byte >> 6;
            gload16((const char*)(Ab + (long)(m0 + row) * lda + k0) + (byte & 63),
                    (char*)As + c * 4096 + wb);
        }
        #pragma unroll
        for (int c = 0; c < NCB; ++c) {
            const int byte = c * 4096 + tb;
            const int row = byte >> 6;
            gload16((const char*)(Bb + (long)(n0 + row) * ldb + k0) + (byte & 63),
                    (char*)Bs + c * 4096 + wb);
        }
        __syncthreads();
        bf16x8 af[MF], bfr[NF];
        #pragma unroll
        for (int m = 0; m < MF; ++m)
            af[m] = *(const bf16x8*)((const char*)As + (wr * WTM + m * 16 + (lane & 15)) * 64 + ko);
        #pragma unroll
        for (int n = 0; n < NF; ++n)
            bfr[n] = *(const bf16x8*)((const char*)Bs + (wc * WTN + n * 16 + (lane & 15)) * 64 + ko);
        #pragma unroll
        for (int m = 0; m < MF; ++m)
            #pragma unroll
            for (int n = 0; n < NF; ++n)
                acc[m][n] = __builtin_amdgcn_mfma_f32_16x16x32_bf16(af[m], bfr[n], acc[m][n], 0, 0, 0);
        __syncthreads();
    }

    const int lr = (lane >> 4) * 4;
    const int lc = lane & 15;

    if constexpr (MODE == M_WQK) {
        // l2-normalize rows over this wave's 64-col slab (== one head),
        // scatter to [H][B][L][KHEAD] bf16, row-XOR-swizzled (for attn_mfma).
        const int h = (n0 + wc * WTN) >> 6;
        #pragma unroll
        for (int m = 0; m < MF; ++m) {
            #pragma unroll
            for (int i = 0; i < 4; ++i) {
                float s = 0.f;
                #pragma unroll
                for (int n = 0; n < NF; ++n) { const float v = acc[m][n][i]; s += v * v; }
                s += __shfl_xor(s, 1); s += __shfl_xor(s, 2);
                s += __shfl_xor(s, 4); s += __shfl_xor(s, 8);
                const float inv = 1.0f / fmaxf(sqrtf(s), 1e-12f);
                const int r = m0 + wr * WTM + m * 16 + lr + i;  // token = l*B + b
                const int l = r >> 5, bq = r & 31;
                const int sw = (l & 7) << 3;
                u16* rowp = C + (((long)(h * BBATCH + bq) * LLEN + l) * KHEAD);
                #pragma unroll
                for (int n = 0; n < NF; ++n)
                    rowp[(lc + n * 16) ^ sw] = f2bf(acc[m][n][i] * inv);
            }
        }
    } else {
        const long cof = h2 * Csh + b2 * Csb;
        #pragma unroll
        for (int m = 0; m < MF; ++m) {
            #pragma unroll
            for (int i = 0; i < 4; ++i) {
                const int r = m0 + wr * WTM + m * 16 + lr + i;
                #pragma unroll
                for (int n = 0; n < NF; ++n) {
                    const int c = n0 + wc * WTN + n * 16 + lc;
                    float v = acc[m][n][i];
                    if (MODE == M_SUBAUX) {
                        const u16* q = (const u16*)auxp;
                        v = bf2f(q[auxsh * h2 + auxsb * b2 + (long)r * auxld + c]) - v;
                    } else if (MODE == M_RELU) {
                        if (bias) v += bias[h2 * biasN + c];
                        v = fmaxf(v, 0.0f);
                    } else if (MODE == M_ADDAUX) {
                        v += bias[h2 * biasN + c];
                        const u16* ax = (const u16*)auxp;
                        v += bf2f(ax[auxsh * h2 + auxsb * b2 + (long)r * auxld + c]);
                    } else if (MODE == M_SCALECOL) {
                        const float* cs = (const float*)auxp + auxsh * h2 + auxsb * b2;
                        v *= 1.0f / (1e-9f + cs[c]);
                    }
                    C[cof + (long)r * ldc + c] = f2bf(v);
                }
            }
        }
    }
}

// MFMA QK^T + softmax (unchanged from round 3).
__global__ __launch_bounds__(256) void attn_mfma(
    const u16* __restrict__ wq, const u16* __restrict__ wk,
    u16* __restrict__ P, float* __restrict__ colsum)
{
    __shared__ u16 qs[64 * 64];
    __shared__ u16 ks[512 * 64];
    __shared__ float smax[4][64];
    __shared__ float ssum[4][64];

    const int qt = blockIdx.x, b = blockIdx.y, h = blockIdx.z;
    const long hb = h * BBATCH + b;
    const int t = threadIdx.x;
    const int lane = t & 63, w = t >> 6;
    const int wb = (t & 192) * 16;

    const char* qg = (const char*)(wq + (hb * LLEN + qt * 64) * KHEAD);
    const char* kg = (const char*)(wk + hb * LLEN * KHEAD);
    #pragma unroll
    for (int c = 0; c < 2; ++c)
        gload16(qg + c * 4096 + t * 16, (char*)qs + c * 4096 + wb);
    #pragma unroll
    for (int c = 0; c < 16; ++c)
        gload16(kg + c * 4096 + t * 16, (char*)ks + c * 4096 + wb);
    __syncthreads();

    const int l15 = lane & 15;
    const int g = lane >> 4;
    const int swz = (lane & 7) << 4;

    f32x4 acc[4][8];
    #pragma unroll
    for (int m = 0; m < 4; ++m)
        #pragma unroll
        for (int n = 0; n < 8; ++n)
            #pragma unroll
            for (int i = 0; i < 4; ++i) acc[m][n][i] = 0.f;

    #pragma unroll
    for (int kk = 0; kk < 2; ++kk) {
        bf16x8 af[4];
        #pragma unroll
        for (int m = 0; m < 4; ++m) {
            const int row = m * 16 + l15;
            af[m] = *(const bf16x8*)((const char*)qs + row * 128 + ((g * 16 + kk * 64) ^ swz));
        }
        #pragma unroll
        for (int n = 0; n < 8; ++n) {
            const int row = (w * 8 + n) * 16 + l15;
            const bf16x8 bfr = *(const bf16x8*)((const char*)ks + row * 128 + ((g * 16 + kk * 64) ^ swz));
            #pragma unroll
            for (int m = 0; m < 4; ++m)
                acc[m][n] = __builtin_amdgcn_mfma_f32_16x16x32_bf16(af[m], bfr, acc[m][n], 0, 0, 0);
        }
    }

    float rmax[4][4];
    #pragma unroll
    for (int m = 0; m < 4; ++m)
        #pragma unroll
        for (int i = 0; i < 4; ++i) {
            float mx = acc[m][0][i];
            #pragma unroll
            for (int n = 1; n < 8; ++n) mx = fmaxf(mx, acc[m][n][i]);
            mx = fmaxf(mx, __shfl_xor(mx, 1));
            mx = fmaxf(mx, __shfl_xor(mx, 2));
            mx = fmaxf(mx, __shfl_xor(mx, 4));
            mx = fmaxf(mx, __shfl_xor(mx, 8));
            if (l15 == 0) smax[w][m * 16 + g * 4 + i] = mx;
        }
    __syncthreads();
    #pragma unroll
    for (int m = 0; m < 4; ++m)
        #pragma unroll
        for (int i = 0; i < 4; ++i) {
            const int r = m * 16 + g * 4 + i;
            rmax[m][i] = fmaxf(fmaxf(smax[0][r], smax[1][r]),
                               fmaxf(smax[2][r], smax[3][r]));
        }
    float rinv[4][4];
    #pragma unroll
    for (int m = 0; m < 4; ++m)
        #pragma unroll
        for (int i = 0; i < 4; ++i) {
            float s = 0.f;
            #pragma unroll
            for (int n = 0; n < 8; ++n) {
                acc[m][n][i] = __expf(acc[m][n][i] - rmax[m][i]);
                s += acc[m][n][i];
            }
            s += __shfl_xor(s, 1); s += __shfl_xor(s, 2);
            s += __shfl_xor(s, 4); s += __shfl_xor(s, 8);
            if (l15 == 0) ssum[w][m * 16 + g * 4 + i] = s;
        }
    __syncthreads();
    #pragma unroll
    for (int m = 0; m < 4; ++m)
        #pragma unroll
        for (int i = 0; i < 4; ++i) {
            const int r = m * 16 + g * 4 + i;
            rinv[m][i] = 1.0f / (ssum[0][r] + ssum[1][r] + ssum[2][r] + ssum[3][r]);
        }

    u16* Pb = P + (hb * LLEN + qt * 64) * LLEN + w * 128;
    float cs[8];
    #pragma unroll
    for (int n = 0; n < 8; ++n) cs[n] = 0.f;
    #pragma unroll
    for (int m = 0; m < 4; ++m)
        #pragma unroll
        for (int i = 0; i < 4; ++i) {
            const int r = m * 16 + g * 4 + i;
            u16* pr = Pb + (long)r * LLEN + l15;
            const float iv = rinv[m][i];
            #pragma unroll
            for (int n = 0; n < 8; ++n) {
                const float p = acc[m][n][i] * iv;
                pr[n * 16] = f2bf(p);
                cs[n] += p;
            }
        }
    #pragma unroll
    for (int n = 0; n < 8; ++n) {
        cs[n] += __shfl_xor(cs[n], 16);
        cs[n] += __shfl_xor(cs[n], 32);
    }
    if (lane < 16) {
        float* cb = colsum + hb * 512 + w * 128 + lane;
        #pragma unroll
        for (int n = 0; n < 8; ++n) atomicAdd(&cb[n * 16], cs[n]);
    }
}

// Fused FFN: per block (128 tokens, head h):
//   phase1: hff = relu(o_tile @ W1^T + b1)   (K=512) -> LDS (swizzled)
//   phase2: preLN = o_tile + hff @ W2^T + b2 (K=64, 4 col-chunks of 128)
__global__ __launch_bounds__(256) void ffn_fused(
    const u16* __restrict__ o, const u16* __restrict__ W1,
    const float* __restrict__ b1, const u16* __restrict__ W2sw,
    const float* __restrict__ b2, u16* __restrict__ preLN)
{
    __shared__ u16 As[128 * 32];    // 8 KB staging (o)
    __shared__ u16 B1s[64 * 32];    // 4 KB staging (W1)
    __shared__ u16 hffs[128 * 64];  // 16 KB, row-swizzled
    __shared__ u16 W2c[128 * 64];   // 16 KB, row-swizzled (linear copy of W2sw)

    const int h = blockIdx.z;
    const int m0 = blockIdx.x * 128;
    const int t = threadIdx.x;
    const int lane = t & 63, w = t >> 6;
    const int l15 = lane & 15, g = lane >> 4;
    const int wb = (t & 192) * 16;
    const u16* ob = o + ((long)h * NTOK + m0) * DDIM;
    const u16* w1b = W1 + h * (FFD * DDIM);

    // ---- phase 1: hff = relu(o @ W1^T + b1), M=128, N=64, K=512 ----
    f32x4 acc[2][4];
    #pragma unroll
    for (int m = 0; m < 2; ++m)
        #pragma unroll
        for (int n = 0; n < 4; ++n)
            #pragma unroll
            for (int i = 0; i < 4; ++i) acc[m][n][i] = 0.f;

    for (int k0 = 0; k0 < 512; k0 += 32) {
        #pragma unroll
        for (int c = 0; c < 2; ++c) {
            const int byte = c * 4096 + t * 16;
            const int row = byte >> 6;
            gload16((const char*)(ob + (long)row * DDIM + k0) + (byte & 63),
                    (char*)As + c * 4096 + wb);
        }
        {
            const int byte = t * 16;
            const int row = byte >> 6;
            gload16((const char*)(w1b + (long)row * DDIM + k0) + (byte & 63),
                    (char*)B1s + wb);
        }
        __syncthreads();
        bf16x8 af[2], bfr[4];
        #pragma unroll
        for (int m = 0; m < 2; ++m)
            af[m] = *(const bf16x8*)((const char*)As + (w * 32 + m * 16 + l15) * 64 + g * 16);
        #pragma unroll
        for (int n = 0; n < 4; ++n)
            bfr[n] = *(const bf16x8*)((const char*)B1s + (n * 16 + l15) * 64 + g * 16);
        #pragma unroll
        for (int m = 0; m < 2; ++m)
            #pragma unroll
            for (int n = 0; n < 4; ++n)
                acc[m][n] = __builtin_amdgcn_mfma_f32_16x16x32_bf16(af[m], bfr[n], acc[m][n], 0, 0, 0);
        __syncthreads();
    }
    // write hff to LDS (bias + relu), row-swizzled
    #pragma unroll
    for (int m = 0; m < 2; ++m)
        #pragma unroll
        for (int i = 0; i < 4; ++i) {
            const int row = w * 32 + m * 16 + g * 4 + i;
            const int sw = (row & 7) << 3;
            #pragma unroll
            for (int n = 0; n < 4; ++n) {
                const int col = n * 16 + l15;
                const float v = fmaxf(acc[m][n][i] + b1[h * FFD + col], 0.0f);
                hffs[row * 64 + (col ^ sw)] = f2bf(v);
            }
        }

    // ---- phase 2: preLN = o + hff @ W2^T + b2, 4 chunks of 128 cols ----
    for (int cc = 0; cc < 4; ++cc) {
        __syncthreads();   // protect W2c from previous chunk's readers
        #pragma unroll
        for (int c = 0; c < 4; ++c) {
            const int byte = c * 4096 + t * 16;
            gload16((const char*)(W2sw + h * 32768) + cc * 16384 + byte,
                    (char*)W2c + c * 4096 + wb);
        }
        __syncthreads();
        f32x4 acc2[2][8];
        #pragma unroll
        for (int m = 0; m < 2; ++m)
            #pragma unroll
            for (int n = 0; n < 8; ++n)
                #pragma unroll
                for (int i = 0; i < 4; ++i) acc2[m][n][i] = 0.f;
        #pragma unroll
        for (int kk = 0; kk < 2; ++kk) {
            bf16x8 paf[2];
            #pragma unroll
            for (int m = 0; m < 2; ++m) {
                const int row = w * 32 + m * 16 + l15;
                paf[m] = *(const bf16x8*)((const char*)hffs + row * 128 +
                                          (((kk * 4 + g) ^ (row & 7)) * 16));
            }
            #pragma unroll
            for (int n = 0; n < 8; ++n) {
                const int row = n * 16 + l15;
                const bf16x8 bfr = *(const bf16x8*)((const char*)W2c + row * 128 +
                                                    (((kk * 4 + g) ^ (row & 7)) * 16));
                #pragma unroll
                for (int m = 0; m < 2; ++m)
                    acc2[m][n] = __builtin_amdgcn_mfma_f32_16x16x32_bf16(paf[m], bfr, acc2[m][n], 0, 0, 0);
            }
        }
        #pragma unroll
        for (int m = 0; m < 2; ++m)
            #pragma unroll
            for (int i = 0; i < 4; ++i) {
                const int row = w * 32 + m * 16 + g * 4 + i;
                #pragma unroll
                for (int n = 0; n < 8; ++n) {
                    const int col = cc * 128 + n * 16 + l15;
                    float v = acc2[m][n][i] + b2[h * DDIM + col] +
                              bf2f(ob[(long)row * DDIM + col]);
                    preLN[((long)h * NTOK + m0 + row) * DDIM + col] = f2bf(v);
                }
            }
    }
}

// LayerNorm over D of preLN[h][b*L+l][:] -> d_out[l][b][h*D+d] fp32
__global__ __launch_bounds__(256) void ln_out(
    const u16* __restrict__ x, const float* __restrict__ g,
    const float* __restrict__ bb, float* __restrict__ out)
{
    const int t = threadIdx.x;
    const int w = t >> 6, lane = t & 63;
    const long row = (long)blockIdx.x * 4 + w;
    const int h = (int)(row >> 14);
    const int t2 = (int)(row & 16383);
    const int b = t2 >> 9, l = t2 & 511;
    const u16* xp = x + row * DDIM;
    float v[8];
    float s = 0.f, sq = 0.f;
    #pragma unroll
    for (int j = 0; j < 8; ++j) {
        v[j] = bf2f(xp[j * 64 + lane]);
        s += v[j]; sq += v[j] * v[j];
    }
    #pragma unroll
    for (int off = 32; off >= 1; off >>= 1) {
        s += __shfl_xor(s, off);
        sq += __shfl_xor(sq, off);
    }
    const float mean = s * (1.0f / 512.0f);
    const float var = sq * (1.0f / 512.0f) - mean * mean;
    const float rs = rsqrtf(var + 1e-5f);
    const float* gp = g + h * DDIM;
    const float* bp = bb + h * DDIM;
    float* op = out + ((long)l * BBATCH + b) * (HH * DDIM) + h * DDIM;
    #pragma unroll
    for (int j = 0; j < 8; ++j) {
        const int d = j * 64 + lane;
        op[d] = (v[j] - mean) * rs * gp[d] + bp[d];
    }
}

extern "C" void kernel_launch(void* const* d_in, const int* in_sizes, int n_in,
                              void* d_out, int out_size, void* d_ws, size_t ws_size,
                              hipStream_t stream) {
    const float* query = (const float*)d_in[0];
    const float* key   = (const float*)d_in[1];
    const float* value = (const float*)d_in[2];
    const float* WK = (const float*)d_in[3];
    const float* WQ = (const float*)d_in[4];
    const float* WV = (const float*)d_in[5];
    const float* Wt = (const float*)d_in[6];
    const float* W1 = (const float*)d_in[7];
    const float* b1 = (const float*)d_in[8];
    const float* W2 = (const float*)d_in[9];
    const float* b2 = (const float*)d_in[10];
    const float* lng = (const float*)d_in[11];
    const float* lnb = (const float*)d_in[12];

    // ---- workspace layout (bytes), peak 319,291,392 ----
    char* ws = (char*)d_ws;
    // [0, 128MB): kbf/WQbf/WKbf until K1; P from K3; preLN at ffn
    u16* kbf  = (u16*)(ws);                    // 16 MB
    u16* WQbf = (u16*)(ws + 16777216);         // 0.5 MB
    u16* WKbf = (u16*)(ws + 17301504);         // 0.5 MB
    u16* P    = (u16*)(ws);                    // 128 MB
    u16* preLN = P;
    // [128MB, 256MB): vbf/WVbf until K2; o from K6
    u16* vbf  = (u16*)(ws + 134217728);        // 16 MB
    u16* WVbf = (u16*)(ws + 150994944);        // 0.5 MB
    u16* o    = (u16*)(ws + 134217728);        // 128 MB
    float* colsum = (float*)(ws + 268435456);  // 0.5 MB
    u16* qbf  = (u16*)(ws + 268959744);        // 16 MB, alive until K5
    // [285736960, 319291392): wq/wk until K3; then Wt/W1/W2 bf16
    u16* wq   = (u16*)(ws + 285736960);
    u16* wk   = (u16*)(ws + 302514176);
    u16* Wtbf = (u16*)(ws + 285736960);        // 4 MB
    u16* W1bf = (u16*)(ws + 289931264);        // 0.5 MB
    u16* W2bf = (u16*)(ws + 290455552);        // 0.5 MB (swizzled)
    // d_out doubles as scratch until ln_out overwrites all of it:
    u16* qmo = (u16*)d_out;                        // [H][B][L][D]
    u16* wvT = (u16*)((char*)d_out + 134217728);   // [H][B][D][L]

    if (ws_size < 319291392u) return;

    hipMemsetAsync(colsum, 0, 524288, stream);
    const dim3 blk(256);

    // fp32 -> bf16 conversions
    f2bf4<<<dim3(8192), blk, 0, stream>>>(query, qbf, 2097152);
    f2bf4<<<dim3(8192), blk, 0, stream>>>(key,   kbf, 2097152);
    f2bf4<<<dim3(8192), blk, 0, stream>>>(value, vbf, 2097152);
    f2bf4<<<dim3(256),  blk, 0, stream>>>(WQ, WQbf, 65536);
    f2bf4<<<dim3(256),  blk, 0, stream>>>(WK, WKbf, 65536);
    f2bf4<<<dim3(2048), blk, 0, stream>>>(WV, WVbf, 524288);

    // K1: wq/wk = l2norm(query/key @ WQ/WK^T) -> [H,B,L,K] bf16 (swizzled rows)
    mgemm<128, 128, M_WQK, 0><<<dim3(128, 4, 1), blk, 0, stream>>>(
        qbf, WQbf, wq, 512, 512, 512, 0,
        0, 0, 0, 0, 0, 0, 1, nullptr, 0, nullptr, 0, 0, 0);
    mgemm<128, 128, M_WQK, 0><<<dim3(128, 4, 1), blk, 0, stream>>>(
        kbf, WKbf, wk, 512, 512, 512, 0,
        0, 0, 0, 0, 0, 0, 1, nullptr, 0, nullptr, 0, 0, 0);

    // K3: MFMA softmax(QK^T) -> P, column sums -> colsum
    attn_mfma<<<dim3(8, 32, 8), blk, 0, stream>>>(wq, wk, P, colsum);

    // weight conversions into the now-dead wq/wk region
    f2bf4<<<dim3(2048), blk, 0, stream>>>(Wt, Wtbf, 524288);
    f2bf4<<<dim3(256),  blk, 0, stream>>>(W1, W1bf, 65536);
    f2bf_w2<<<dim3(128), blk, 0, stream>>>(W2, W2bf);

    // K2: wvT[h,b,e,l] = (sum_d WV[h,e,d]*value[l,b,d]) / (1e-9+colsum[h,b,l])
    // grouped z-map: WV reused across adjacent b, value reused across adjacent h
    mgemm<128, 128, M_SCALECOL, 2><<<dim3(4, 4, 256), blk, 0, stream>>>(
        WVbf, vbf, wvT, 512, 512, BBATCH * DDIM, 512,
        (long)DDIM * DDIM, 0, 0, DDIM,
        (long)BBATCH * DDIM * LLEN, (long)DDIM * LLEN, 32,
        nullptr, 0, colsum, (long)BBATCH * 512, 512, 0);

    // K5: qmo = query - P @ wvT^T   (b-major: aux rows L2-reused across h)
    mgemm<128, 128, M_SUBAUX, 1><<<dim3(4, 4, 256), blk, 0, stream>>>(
        P, wvT, qmo, 512, 512, 512, 512,
        (long)BBATCH * LLEN * LLEN, (long)LLEN * LLEN,
        (long)BBATCH * DDIM * LLEN, (long)DDIM * LLEN,
        (long)BBATCH * LLEN * DDIM, (long)LLEN * DDIM, 32,
        nullptr, 0, qbf, 0, DDIM, BBATCH * DDIM);

    // K6: o = relu(qmo @ Wt^T)
    mgemm<128, 128, M_RELU, 0><<<dim3(128, 4, 8), blk, 0, stream>>>(
        qmo, Wtbf, o, 512, 512, 512, 512,
        (long)NTOK * DDIM, 0, (long)DDIM * DDIM, 0,
        (long)NTOK * DDIM, 0, 1, nullptr, 512, nullptr, 0, 0, 0);

    // K7+K8 fused: preLN = o + relu(o@W1^T+b1)@W2^T + b2
    ffn_fused<<<dim3(128, 1, 8), blk, 0, stream>>>(o, W1bf, b1, W2bf, b2, preLN);

    // K9: LayerNorm + transpose-scatter to [L,B,H*D] fp32
    ln_out<<<dim3(32768), blk, 0, stream>>>(preLN, lng, lnb, (float*)d_out);
}

// Round 5
// 803.359 us; speedup vs baseline: 1.1645x; 1.1645x over previous
//
#include <hip/hip_runtime.h>
#include <stdint.h>

#define HH 8
#define DDIM 512
#define KHEAD 64
#define FFD 64
#define LLEN 512
#define BBATCH 32
#define NTOK 16384  // L*B

typedef unsigned short u16;
typedef __attribute__((ext_vector_type(8))) __bf16 bf16x8;
typedef __attribute__((ext_vector_type(4))) float f32x4;

__device__ __forceinline__ float bf2f(u16 u) {
    union { uint32_t i; float f; } v; v.i = ((uint32_t)u) << 16; return v.f;
}
__device__ __forceinline__ u16 f2bf(float f) {
    union { uint32_t i; float f; } v; v.f = f;
    return (u16)((v.i + 0x7FFFu + ((v.i >> 16) & 1u)) >> 16);
}

__device__ __forceinline__ void gload16(const void* g, void* l) {
    __builtin_amdgcn_global_load_lds(
        (const __attribute__((address_space(1))) void*)g,
        (__attribute__((address_space(3))) void*)l, 16, 0, 0);
}

// fp32 -> bf16 (RNE), 4 elems/thread
__global__ __launch_bounds__(256) void f2bf4(const float* __restrict__ in,
                                             u16* __restrict__ out, int n4) {
    int i = blockIdx.x * 256 + threadIdx.x;
    if (i >= n4) return;
    float4 v = ((const float4*)in)[i];
    ushort4 o; o.x = f2bf(v.x); o.y = f2bf(v.y); o.z = f2bf(v.z); o.w = f2bf(v.w);
    ((ushort4*)out)[i] = o;
}

enum { M_PLAIN = 0, M_WQK = 1, M_SUBAUX = 2, M_RELU = 3, M_ADDAUX = 4, M_SCALECOL = 5 };

// MFMA batched GEMM, both operands K-contiguous ("B^T form"):
//   C[m,n] = sum_k A[m,k] * B[n,k]   (bf16 in, fp32 acc, bf16 out)
// ZMAP: 0 = h-major (h2=z/nB2, b2=z%nB2); 1 = b-major (h2=z&7, b2=z>>3);
//       2 = grouped 8h x 8b (h2=(z>>3)&7, b2=(z>>6)*8 + (z&7)).
// SWAPXY: 1 = m-tile index taken from blockIdx.y (n-tiles vary fastest ->
//         consecutive blocks share the A-tile; A fetched ~once from HBM).
template<int BM, int BN, int MODE, int ZMAP, int SWAPXY>
__global__ __launch_bounds__(256) void mgemm(
    const u16* __restrict__ A, const u16* __restrict__ B, u16* __restrict__ C,
    int Kd, int lda, int ldb, int ldc,
    long Ash, long Asb, long Bsh, long Bsb, long Csh, long Csb, int nB2,
    const float* __restrict__ bias, int biasN,
    const void* __restrict__ auxp, long auxsh, long auxsb, int auxld)
{
    constexpr int WC = (BN == 128) ? 2 : 1;
    constexpr int WR = 4 / WC;
    constexpr int WTM = BM / WR;
    constexpr int WTN = BN / WC;
    constexpr int MF = WTM / 16;
    constexpr int NF = WTN / 16;
    constexpr int NCA = (BM * 64) / 4096;
    constexpr int NCB = (BN * 64) / 4096;
    __shared__ u16 As[BM * 32];
    __shared__ u16 Bs[BN * 32];

    const int z = blockIdx.z;
    int h2, b2;
    if (ZMAP == 0)      { h2 = z / nB2;      b2 = z % nB2; }
    else if (ZMAP == 1) { h2 = z & 7;        b2 = z >> 3; }
    else                { h2 = (z >> 3) & 7; b2 = ((z >> 6) << 3) | (z & 7); }
    const u16* Ab = A + h2 * Ash + b2 * Asb;
    const u16* Bb = B + h2 * Bsh + b2 * Bsb;
    const int bx = SWAPXY ? blockIdx.y : blockIdx.x;
    const int by = SWAPXY ? blockIdx.x : blockIdx.y;
    const int m0 = bx * BM, n0 = by * BN;
    const int t = threadIdx.x;
    const int lane = t & 63;
    const int w = t >> 6;
    const int wr = w / WC, wc = w % WC;
    const int tb = t * 16;
    const int wb = (t & 192) * 16;

    f32x4 acc[MF][NF];
    #pragma unroll
    for (int m = 0; m < MF; ++m)
        #pragma unroll
        for (int n = 0; n < NF; ++n)
            #pragma unroll
            for (int i = 0; i < 4; ++i) acc[m][n][i] = 0.f;

    const int ko = (lane >> 4) * 16;

    for (int k0 = 0; k0 < Kd; k0 += 32) {
        #pragma unroll
        for (int c = 0; c < NCA; ++c) {
            const int byte = c * 4096 + tb;
            const int row = byte >> 6;
            gload16((const char*)(Ab + (long)(m0 + row) * lda + k0) + (byte & 63),
                    (char*)As + c * 4096 + wb);
        }
        #pragma unroll
        for (int c = 0; c < NCB; ++c) {
            const int byte = c * 4096 + tb;
            const int row = byte >> 6;
            gload16((const char*)(Bb + (long)(n0 + row) * ldb + k0) + (byte & 63),
                    (char*)Bs + c * 4096 + wb);
        }
        __syncthreads();
        bf16x8 af[MF], bfr[NF];
        #pragma unroll
        for (int m = 0; m < MF; ++m)
            af[m] = *(const bf16x8*)((const char*)As + (wr * WTM + m * 16 + (lane & 15)) * 64 + ko);
        #pragma unroll
        for (int n = 0; n < NF; ++n)
            bfr[n] = *(const bf16x8*)((const char*)Bs + (wc * WTN + n * 16 + (lane & 15)) * 64 + ko);
        #pragma unroll
        for (int m = 0; m < MF; ++m)
            #pragma unroll
            for (int n = 0; n < NF; ++n)
                acc[m][n] = __builtin_amdgcn_mfma_f32_16x16x32_bf16(af[m], bfr[n], acc[m][n], 0, 0, 0);
        __syncthreads();
    }

    const int lr = (lane >> 4) * 4;
    const int lc = lane & 15;

    if constexpr (MODE == M_WQK) {
        // l2-normalize rows over this wave's 64-col slab (== one head),
        // scatter to [H][B][L][KHEAD] bf16, row-XOR-swizzled (for attn_mfma).
        const int h = (n0 + wc * WTN) >> 6;
        #pragma unroll
        for (int m = 0; m < MF; ++m) {
            #pragma unroll
            for (int i = 0; i < 4; ++i) {
                float s = 0.f;
                #pragma unroll
                for (int n = 0; n < NF; ++n) { const float v = acc[m][n][i]; s += v * v; }
                s += __shfl_xor(s, 1); s += __shfl_xor(s, 2);
                s += __shfl_xor(s, 4); s += __shfl_xor(s, 8);
                const float inv = 1.0f / fmaxf(sqrtf(s), 1e-12f);
                const int r = m0 + wr * WTM + m * 16 + lr + i;  // token = l*B + b
                const int l = r >> 5, bq = r & 31;
                const int sw = (l & 7) << 3;
                u16* rowp = C + (((long)(h * BBATCH + bq) * LLEN + l) * KHEAD);
                #pragma unroll
                for (int n = 0; n < NF; ++n)
                    rowp[(lc + n * 16) ^ sw] = f2bf(acc[m][n][i] * inv);
            }
        }
    } else {
        const long cof = h2 * Csh + b2 * Csb;
        #pragma unroll
        for (int m = 0; m < MF; ++m) {
            #pragma unroll
            for (int i = 0; i < 4; ++i) {
                const int r = m0 + wr * WTM + m * 16 + lr + i;
                #pragma unroll
                for (int n = 0; n < NF; ++n) {
                    const int c = n0 + wc * WTN + n * 16 + lc;
                    float v = acc[m][n][i];
                    if (MODE == M_SUBAUX) {
                        const u16* q = (const u16*)auxp;
                        v = bf2f(q[auxsh * h2 + auxsb * b2 + (long)r * auxld + c]) - v;
                    } else if (MODE == M_RELU) {
                        if (bias) v += bias[h2 * biasN + c];
                        v = fmaxf(v, 0.0f);
                    } else if (MODE == M_ADDAUX) {
                        v += bias[h2 * biasN + c];
                        const u16* ax = (const u16*)auxp;
                        v += bf2f(ax[auxsh * h2 + auxsb * b2 + (long)r * auxld + c]);
                    } else if (MODE == M_SCALECOL) {
                        const float* cs = (const float*)auxp + auxsh * h2 + auxsb * b2;
                        v *= 1.0f / (1e-9f + cs[c]);
                    }
                    C[cof + (long)r * ldc + c] = f2bf(v);
                }
            }
        }
    }
}

// MFMA QK^T + softmax: block = (qt, b, h) covers 64 q-rows x all 512 k.
__global__ __launch_bounds__(256) void attn_mfma(
    const u16* __restrict__ wq, const u16* __restrict__ wk,
    u16* __restrict__ P, float* __restrict__ colsum)
{
    __shared__ u16 qs[64 * 64];
    __shared__ u16 ks[512 * 64];
    __shared__ float smax[4][64];
    __shared__ float ssum[4][64];

    const int qt = blockIdx.x, b = blockIdx.y, h = blockIdx.z;
    const long hb = h * BBATCH + b;
    const int t = threadIdx.x;
    const int lane = t & 63, w = t >> 6;
    const int wb = (t & 192) * 16;

    const char* qg = (const char*)(wq + (hb * LLEN + qt * 64) * KHEAD);
    const char* kg = (const char*)(wk + hb * LLEN * KHEAD);
    #pragma unroll
    for (int c = 0; c < 2; ++c)
        gload16(qg + c * 4096 + t * 16, (char*)qs + c * 4096 + wb);
    #pragma unroll
    for (int c = 0; c < 16; ++c)
        gload16(kg + c * 4096 + t * 16, (char*)ks + c * 4096 + wb);
    __syncthreads();

    const int l15 = lane & 15;
    const int g = lane >> 4;
    const int swz = (lane & 7) << 4;

    f32x4 acc[4][8];
    #pragma unroll
    for (int m = 0; m < 4; ++m)
        #pragma unroll
        for (int n = 0; n < 8; ++n)
            #pragma unroll
            for (int i = 0; i < 4; ++i) acc[m][n][i] = 0.f;

    #pragma unroll
    for (int kk = 0; kk < 2; ++kk) {
        bf16x8 af[4];
        #pragma unroll
        for (int m = 0; m < 4; ++m) {
            const int row = m * 16 + l15;
            af[m] = *(const bf16x8*)((const char*)qs + row * 128 + ((g * 16 + kk * 64) ^ swz));
        }
        #pragma unroll
        for (int n = 0; n < 8; ++n) {
            const int row = (w * 8 + n) * 16 + l15;
            const bf16x8 bfr = *(const bf16x8*)((const char*)ks + row * 128 + ((g * 16 + kk * 64) ^ swz));
            #pragma unroll
            for (int m = 0; m < 4; ++m)
                acc[m][n] = __builtin_amdgcn_mfma_f32_16x16x32_bf16(af[m], bfr, acc[m][n], 0, 0, 0);
        }
    }

    float rmax[4][4];
    #pragma unroll
    for (int m = 0; m < 4; ++m)
        #pragma unroll
        for (int i = 0; i < 4; ++i) {
            float mx = acc[m][0][i];
            #pragma unroll
            for (int n = 1; n < 8; ++n) mx = fmaxf(mx, acc[m][n][i]);
            mx = fmaxf(mx, __shfl_xor(mx, 1));
            mx = fmaxf(mx, __shfl_xor(mx, 2));
            mx = fmaxf(mx, __shfl_xor(mx, 4));
            mx = fmaxf(mx, __shfl_xor(mx, 8));
            if (l15 == 0) smax[w][m * 16 + g * 4 + i] = mx;
        }
    __syncthreads();
    #pragma unroll
    for (int m = 0; m < 4; ++m)
        #pragma unroll
        for (int i = 0; i < 4; ++i) {
            const int r = m * 16 + g * 4 + i;
            rmax[m][i] = fmaxf(fmaxf(smax[0][r], smax[1][r]),
                               fmaxf(smax[2][r], smax[3][r]));
        }
    float rinv[4][4];
    #pragma unroll
    for (int m = 0; m < 4; ++m)
        #pragma unroll
        for (int i = 0; i < 4; ++i) {
            float s = 0.f;
            #pragma unroll
            for (int n = 0; n < 8; ++n) {
                acc[m][n][i] = __expf(acc[m][n][i] - rmax[m][i]);
                s += acc[m][n][i];
            }
            s += __shfl_xor(s, 1); s += __shfl_xor(s, 2);
            s += __shfl_xor(s, 4); s += __shfl_xor(s, 8);
            if (l15 == 0) ssum[w][m * 16 + g * 4 + i] = s;
        }
    __syncthreads();
    #pragma unroll
    for (int m = 0; m < 4; ++m)
        #pragma unroll
        for (int i = 0; i < 4; ++i) {
            const int r = m * 16 + g * 4 + i;
            rinv[m][i] = 1.0f / (ssum[0][r] + ssum[1][r] + ssum[2][r] + ssum[3][r]);
        }

    u16* Pb = P + (hb * LLEN + qt * 64) * LLEN + w * 128;
    float cs[8];
    #pragma unroll
    for (int n = 0; n < 8; ++n) cs[n] = 0.f;
    #pragma unroll
    for (int m = 0; m < 4; ++m)
        #pragma unroll
        for (int i = 0; i < 4; ++i) {
            const int r = m * 16 + g * 4 + i;
            u16* pr = Pb + (long)r * LLEN + l15;
            const float iv = rinv[m][i];
            #pragma unroll
            for (int n = 0; n < 8; ++n) {
                const float p = acc[m][n][i] * iv;
                pr[n * 16] = f2bf(p);
                cs[n] += p;
            }
        }
    #pragma unroll
    for (int n = 0; n < 8; ++n) {
        cs[n] += __shfl_xor(cs[n], 16);
        cs[n] += __shfl_xor(cs[n], 32);
    }
    if (lane < 16) {
        float* cb = colsum + hb * 512 + w * 128 + lane;
        #pragma unroll
        for (int n = 0; n < 8; ++n) atomicAdd(&cb[n * 16], cs[n]);
    }
}

// LayerNorm over D of preLN[h][b*L+l][:] -> d_out[l][b][h*D+d] fp32
__global__ __launch_bounds__(256) void ln_out(
    const u16* __restrict__ x, const float* __restrict__ g,
    const float* __restrict__ bb, float* __restrict__ out)
{
    const int t = threadIdx.x;
    const int w = t >> 6, lane = t & 63;
    const long row = (long)blockIdx.x * 4 + w;
    const int h = (int)(row >> 14);
    const int t2 = (int)(row & 16383);
    const int b = t2 >> 9, l = t2 & 511;
    const u16* xp = x + row * DDIM;
    float v[8];
    float s = 0.f, sq = 0.f;
    #pragma unroll
    for (int j = 0; j < 8; ++j) {
        v[j] = bf2f(xp[j * 64 + lane]);
        s += v[j]; sq += v[j] * v[j];
    }
    #pragma unroll
    for (int off = 32; off >= 1; off >>= 1) {
        s += __shfl_xor(s, off);
        sq += __shfl_xor(sq, off);
    }
    const float mean = s * (1.0f / 512.0f);
    const float var = sq * (1.0f / 512.0f) - mean * mean;
    const float rs = rsqrtf(var + 1e-5f);
    const float* gp = g + h * DDIM;
    const float* bp = bb + h * DDIM;
    float* op = out + ((long)l * BBATCH + b) * (HH * DDIM) + h * DDIM;
    #pragma unroll
    for (int j = 0; j < 8; ++j) {
        const int d = j * 64 + lane;
        op[d] = (v[j] - mean) * rs * gp[d] + bp[d];
    }
}

extern "C" void kernel_launch(void* const* d_in, const int* in_sizes, int n_in,
                              void* d_out, int out_size, void* d_ws, size_t ws_size,
                              hipStream_t stream) {
    const float* query = (const float*)d_in[0];
    const float* key   = (const float*)d_in[1];
    const float* value = (const float*)d_in[2];
    const float* WK = (const float*)d_in[3];
    const float* WQ = (const float*)d_in[4];
    const float* WV = (const float*)d_in[5];
    const float* Wt = (const float*)d_in[6];
    const float* W1 = (const float*)d_in[7];
    const float* b1 = (const float*)d_in[8];
    const float* W2 = (const float*)d_in[9];
    const float* b2 = (const float*)d_in[10];
    const float* lng = (const float*)d_in[11];
    const float* lnb = (const float*)d_in[12];

    // ---- workspace layout (bytes), peak 319,291,392 ----
    char* ws = (char*)d_ws;
    // [0, 128MB): kbf/WQbf/WKbf until K1; P from K3; preLN at K8
    u16* kbf  = (u16*)(ws);                    // 16 MB
    u16* WQbf = (u16*)(ws + 16777216);         // 0.5 MB
    u16* WKbf = (u16*)(ws + 17301504);         // 0.5 MB
    u16* P    = (u16*)(ws);                    // 128 MB
    u16* preLN = P;
    // [128MB, 256MB): vbf/WVbf until K2; o from K6
    u16* vbf  = (u16*)(ws + 134217728);        // 16 MB
    u16* WVbf = (u16*)(ws + 150994944);        // 0.5 MB
    u16* o    = (u16*)(ws + 134217728);        // 128 MB
    float* colsum = (float*)(ws + 268435456);  // 0.5 MB
    u16* qbf  = (u16*)(ws + 268959744);        // 16 MB, dead after K5
    u16* hff  = qbf;                           // 16 MB, produced at K7
    // [285736960, 319291392): wq/wk until K3; then Wt/W1/W2 bf16
    u16* wq   = (u16*)(ws + 285736960);
    u16* wk   = (u16*)(ws + 302514176);
    u16* Wtbf = (u16*)(ws + 285736960);        // 4 MB
    u16* W1bf = (u16*)(ws + 289931264);        // 0.5 MB
    u16* W2bf = (u16*)(ws + 290455552);        // 0.5 MB
    // d_out doubles as scratch until ln_out overwrites all of it:
    u16* qmo = (u16*)d_out;                        // [H][B][L][D]
    u16* wvT = (u16*)((char*)d_out + 134217728);   // [H][B][D][L]

    if (ws_size < 319291392u) return;

    hipMemsetAsync(colsum, 0, 524288, stream);
    const dim3 blk(256);

    // fp32 -> bf16 conversions
    f2bf4<<<dim3(8192), blk, 0, stream>>>(query, qbf, 2097152);
    f2bf4<<<dim3(8192), blk, 0, stream>>>(key,   kbf, 2097152);
    f2bf4<<<dim3(8192), blk, 0, stream>>>(value, vbf, 2097152);
    f2bf4<<<dim3(256),  blk, 0, stream>>>(WQ, WQbf, 65536);
    f2bf4<<<dim3(256),  blk, 0, stream>>>(WK, WKbf, 65536);
    f2bf4<<<dim3(2048), blk, 0, stream>>>(WV, WVbf, 524288);

    // K1: wq/wk = l2norm(query/key @ WQ/WK^T) -> [H,B,L,K] bf16 (swizzled rows)
    // SWAPXY: 4 n-tiles fastest -> A-tile L2-reused, A fetched ~once
    mgemm<128, 128, M_WQK, 0, 1><<<dim3(4, 128, 1), blk, 0, stream>>>(
        qbf, WQbf, wq, 512, 512, 512, 0,
        0, 0, 0, 0, 0, 0, 1, nullptr, 0, nullptr, 0, 0, 0);
    mgemm<128, 128, M_WQK, 0, 1><<<dim3(4, 128, 1), blk, 0, stream>>>(
        kbf, WKbf, wk, 512, 512, 512, 0,
        0, 0, 0, 0, 0, 0, 1, nullptr, 0, nullptr, 0, 0, 0);

    // K3: MFMA softmax(QK^T) -> P, column sums -> colsum
    attn_mfma<<<dim3(8, 32, 8), blk, 0, stream>>>(wq, wk, P, colsum);

    // weight conversions into the now-dead wq/wk region
    f2bf4<<<dim3(2048), blk, 0, stream>>>(Wt, Wtbf, 524288);
    f2bf4<<<dim3(256),  blk, 0, stream>>>(W1, W1bf, 65536);
    f2bf4<<<dim3(256),  blk, 0, stream>>>(W2, W2bf, 65536);

    // K2: wvT[h,b,e,l] = (sum_d WV[h,e,d]*value[l,b,d]) / (1e-9+colsum[h,b,l])
    mgemm<128, 128, M_SCALECOL, 2, 0><<<dim3(4, 4, 256), blk, 0, stream>>>(
        WVbf, vbf, wvT, 512, 512, BBATCH * DDIM, 512,
        (long)DDIM * DDIM, 0, 0, DDIM,
        (long)BBATCH * DDIM * LLEN, (long)DDIM * LLEN, 32,
        nullptr, 0, colsum, (long)BBATCH * 512, 512, 0);

    // K5: qmo = query - P @ wvT^T   (b-major: aux rows L2-reused across h)
    mgemm<128, 128, M_SUBAUX, 1, 0><<<dim3(4, 4, 256), blk, 0, stream>>>(
        P, wvT, qmo, 512, 512, 512, 512,
        (long)BBATCH * LLEN * LLEN, (long)LLEN * LLEN,
        (long)BBATCH * DDIM * LLEN, (long)DDIM * LLEN,
        (long)BBATCH * LLEN * DDIM, (long)LLEN * DDIM, 32,
        nullptr, 0, qbf, 0, DDIM, BBATCH * DDIM);

    // K6: o = relu(qmo @ Wt^T)   (SWAPXY: qmo fetched ~once, Wt L2-resident)
    mgemm<128, 128, M_RELU, 0, 1><<<dim3(4, 128, 8), blk, 0, stream>>>(
        qmo, Wtbf, o, 512, 512, 512, 512,
        (long)NTOK * DDIM, 0, (long)DDIM * DDIM, 0,
        (long)NTOK * DDIM, 0, 1, nullptr, 512, nullptr, 0, 0, 0);

    // K7: hff = relu(o @ W1^T + b1)   (BN=64)
    mgemm<128, 64, M_RELU, 0, 0><<<dim3(128, 1, 8), blk, 0, stream>>>(
        o, W1bf, hff, 512, 512, 512, 64,
        (long)NTOK * DDIM, 0, (long)FFD * DDIM, 0,
        (long)NTOK * FFD, 0, 1, b1, 64, nullptr, 0, 0, 0);

    // K8: preLN = o + (hff @ W2^T + b2)   (Kd=64, SWAPXY)
    mgemm<128, 128, M_ADDAUX, 0, 1><<<dim3(4, 128, 8), blk, 0, stream>>>(
        hff, W2bf, preLN, 64, 64, 64, 512,
        (long)NTOK * FFD, 0, (long)DDIM * FFD, 0,
        (long)NTOK * DDIM, 0, 1, b2, 512, o, (long)NTOK * DDIM, 0, 512);

    // K9: LayerNorm + transpose-scatter to [L,B,H*D] fp32
    ln_out<<<dim3(32768), blk, 0, stream>>>(preLN, lng, lnb, (float*)d_out);
}

// Round 7
// 771.764 us; speedup vs baseline: 1.2122x; 1.0409x over previous
//
#include <hip/hip_runtime.h>
#include <stdint.h>

#define HH 8
#define DDIM 512
#define KHEAD 64
#define FFD 64
#define LLEN 512
#define BBATCH 32
#define NTOK 16384  // L*B

typedef unsigned short u16;
typedef __attribute__((ext_vector_type(8))) __bf16 bf16x8;
typedef __attribute__((ext_vector_type(4))) float f32x4;

__device__ __forceinline__ float bf2f(u16 u) {
    union { uint32_t i; float f; } v; v.i = ((uint32_t)u) << 16; return v.f;
}
__device__ __forceinline__ u16 f2bf(float f) {
    union { uint32_t i; float f; } v; v.f = f;
    return (u16)((v.i + 0x7FFFu + ((v.i >> 16) & 1u)) >> 16);
}

__device__ __forceinline__ void gload16(const void* g, void* l) {
    __builtin_amdgcn_global_load_lds(
        (const __attribute__((address_space(1))) void*)g,
        (__attribute__((address_space(3))) void*)l, 16, 0, 0);
}

// fp32 -> bf16 (RNE), 4 elems/thread
__global__ __launch_bounds__(256) void f2bf4(const float* __restrict__ in,
                                             u16* __restrict__ out, int n4) {
    int i = blockIdx.x * 256 + threadIdx.x;
    if (i >= n4) return;
    float4 v = ((const float4*)in)[i];
    ushort4 o; o.x = f2bf(v.x); o.y = f2bf(v.y); o.z = f2bf(v.z); o.w = f2bf(v.w);
    ((ushort4*)out)[i] = o;
}

enum { M_PLAIN = 0, M_WQK = 1, M_SUBAUX = 2, M_RELU = 3, M_ADDAUX = 4, M_SCALECOL = 5 };

// MFMA batched GEMM, both operands K-contiguous ("B^T form"):
//   C[m,n] = sum_k A[m,k] * B[n,k]   (bf16 in, fp32 acc, bf16 out)
// 2-phase double-buffered: STAGE(next) issued before compute(cur); single
// barrier per K-step (drains vmcnt after MFMA covers the load latency).
template<int BM, int BN, int MODE, int ZMAP, int SWAPXY>
__global__ __launch_bounds__(256) void mgemm(
    const u16* __restrict__ A, const u16* __restrict__ B, u16* __restrict__ C,
    int Kd, int lda, int ldb, int ldc,
    long Ash, long Asb, long Bsh, long Bsb, long Csh, long Csb, int nB2,
    const float* __restrict__ bias, int biasN,
    const void* __restrict__ auxp, long auxsh, long auxsb, int auxld)
{
    constexpr int WC = (BN == 128) ? 2 : 1;
    constexpr int WR = 4 / WC;
    constexpr int WTM = BM / WR;
    constexpr int WTN = BN / WC;
    constexpr int MF = WTM / 16;
    constexpr int NF = WTN / 16;
    constexpr int NCA = (BM * 64) / 4096;
    constexpr int NCB = (BN * 64) / 4096;
    __shared__ u16 As[2][BM * 32];
    __shared__ u16 Bs[2][BN * 32];

    const int z = blockIdx.z;
    int h2, b2;
    if (ZMAP == 0)      { h2 = z / nB2;      b2 = z % nB2; }
    else if (ZMAP == 1) { h2 = z & 7;        b2 = z >> 3; }
    else                { h2 = (z >> 3) & 7; b2 = ((z >> 6) << 3) | (z & 7); }
    const u16* Ab = A + h2 * Ash + b2 * Asb;
    const u16* Bb = B + h2 * Bsh + b2 * Bsb;
    const int bx = SWAPXY ? blockIdx.y : blockIdx.x;
    const int by = SWAPXY ? blockIdx.x : blockIdx.y;
    const int m0 = bx * BM, n0 = by * BN;
    const int t = threadIdx.x;
    const int lane = t & 63;
    const int w = t >> 6;
    const int wr = w / WC, wc = w % WC;
    const int tb = t * 16;
    const int wb = (t & 192) * 16;

    f32x4 acc[MF][NF];
    #pragma unroll
    for (int m = 0; m < MF; ++m)
        #pragma unroll
        for (int n = 0; n < NF; ++n)
            #pragma unroll
            for (int i = 0; i < 4; ++i) acc[m][n][i] = 0.f;

    const int ko = (lane >> 4) * 16;

    auto stage = [&](int buf, int k0) {
        #pragma unroll
        for (int c = 0; c < NCA; ++c) {
            const int byte = c * 4096 + tb;
            const int row = byte >> 6;
            gload16((const char*)(Ab + (long)(m0 + row) * lda + k0) + (byte & 63),
                    (char*)As[buf] + c * 4096 + wb);
        }
        #pragma unroll
        for (int c = 0; c < NCB; ++c) {
            const int byte = c * 4096 + tb;
            const int row = byte >> 6;
            gload16((const char*)(Bb + (long)(n0 + row) * ldb + k0) + (byte & 63),
                    (char*)Bs[buf] + c * 4096 + wb);
        }
    };

    stage(0, 0);
    __syncthreads();          // prologue drain: buf0 ready
    int cur = 0;
    const int nsteps = Kd >> 5;
    for (int s = 0; s < nsteps; ++s) {
        if (s + 1 < nsteps) stage(cur ^ 1, (s + 1) << 5);   // issue, no wait
        bf16x8 af[MF], bfr[NF];
        #pragma unroll
        for (int m = 0; m < MF; ++m)
            af[m] = *(const bf16x8*)((const char*)As[cur] + (wr * WTM + m * 16 + (lane & 15)) * 64 + ko);
        #pragma unroll
        for (int n = 0; n < NF; ++n)
            bfr[n] = *(const bf16x8*)((const char*)Bs[cur] + (wc * WTN + n * 16 + (lane & 15)) * 64 + ko);
        #pragma unroll
        for (int m = 0; m < MF; ++m)
            #pragma unroll
            for (int n = 0; n < NF; ++n)
                acc[m][n] = __builtin_amdgcn_mfma_f32_16x16x32_bf16(af[m], bfr[n], acc[m][n], 0, 0, 0);
        __syncthreads();      // drains this step's reads AND next-tile stage
        cur ^= 1;
    }

    const int lr = (lane >> 4) * 4;
    const int lc = lane & 15;

    if constexpr (MODE == M_WQK) {
        // l2-normalize rows over this wave's 64-col slab (== one head),
        // scatter to [H][B][L][KHEAD] bf16, row-XOR-swizzled (for attn_mfma).
        const int h = (n0 + wc * WTN) >> 6;
        #pragma unroll
        for (int m = 0; m < MF; ++m) {
            #pragma unroll
            for (int i = 0; i < 4; ++i) {
                float s = 0.f;
                #pragma unroll
                for (int n = 0; n < NF; ++n) { const float v = acc[m][n][i]; s += v * v; }
                s += __shfl_xor(s, 1); s += __shfl_xor(s, 2);
                s += __shfl_xor(s, 4); s += __shfl_xor(s, 8);
                const float inv = 1.0f / fmaxf(sqrtf(s), 1e-12f);
                const int r = m0 + wr * WTM + m * 16 + lr + i;  // token = l*B + b
                const int l = r >> 5, bq = r & 31;
                const int sw = (l & 7) << 3;
                u16* rowp = C + (((long)(h * BBATCH + bq) * LLEN + l) * KHEAD);
                #pragma unroll
                for (int n = 0; n < NF; ++n)
                    rowp[(lc + n * 16) ^ sw] = f2bf(acc[m][n][i] * inv);
            }
        }
    } else {
        const long cof = h2 * Csh + b2 * Csb;
        #pragma unroll
        for (int m = 0; m < MF; ++m) {
            #pragma unroll
            for (int i = 0; i < 4; ++i) {
                const int r = m0 + wr * WTM + m * 16 + lr + i;
                #pragma unroll
                for (int n = 0; n < NF; ++n) {
                    const int c = n0 + wc * WTN + n * 16 + lc;
                    float v = acc[m][n][i];
                    if (MODE == M_SUBAUX) {
                        const u16* q = (const u16*)auxp;
                        v = bf2f(q[auxsh * h2 + auxsb * b2 + (long)r * auxld + c]) - v;
                    } else if (MODE == M_RELU) {
                        if (bias) v += bias[h2 * biasN + c];
                        v = fmaxf(v, 0.0f);
                    } else if (MODE == M_ADDAUX) {
                        v += bias[h2 * biasN + c];
                        const u16* ax = (const u16*)auxp;
                        v += bf2f(ax[auxsh * h2 + auxsb * b2 + (long)r * auxld + c]);
                    } else if (MODE == M_SCALECOL) {
                        const float* cs = (const float*)auxp + auxsh * h2 + auxsb * b2;
                        v *= 1.0f / (1e-9f + cs[c]);
                    }
                    C[cof + (long)r * ldc + c] = f2bf(v);
                }
            }
        }
    }
}

// MFMA QK^T + softmax: block = (qt, b, h) covers 64 q-rows x all 512 k.
__global__ __launch_bounds__(256) void attn_mfma(
    const u16* __restrict__ wq, const u16* __restrict__ wk,
    u16* __restrict__ P, float* __restrict__ colsum)
{
    __shared__ u16 qs[64 * 64];
    __shared__ u16 ks[512 * 64];
    __shared__ float smax[4][64];
    __shared__ float ssum[4][64];

    const int qt = blockIdx.x, b = blockIdx.y, h = blockIdx.z;
    const long hb = h * BBATCH + b;
    const int t = threadIdx.x;
    const int lane = t & 63, w = t >> 6;
    const int wb = (t & 192) * 16;

    const char* qg = (const char*)(wq + (hb * LLEN + qt * 64) * KHEAD);
    const char* kg = (const char*)(wk + hb * LLEN * KHEAD);
    #pragma unroll
    for (int c = 0; c < 2; ++c)
        gload16(qg + c * 4096 + t * 16, (char*)qs + c * 4096 + wb);
    #pragma unroll
    for (int c = 0; c < 16; ++c)
        gload16(kg + c * 4096 + t * 16, (char*)ks + c * 4096 + wb);
    __syncthreads();

    const int l15 = lane & 15;
    const int g = lane >> 4;
    const int swz = (lane & 7) << 4;

    f32x4 acc[4][8];
    #pragma unroll
    for (int m = 0; m < 4; ++m)
        #pragma unroll
        for (int n = 0; n < 8; ++n)
            #pragma unroll
            for (int i = 0; i < 4; ++i) acc[m][n][i] = 0.f;

    #pragma unroll
    for (int kk = 0; kk < 2; ++kk) {
        bf16x8 af[4];
        #pragma unroll
        for (int m = 0; m < 4; ++m) {
            const int row = m * 16 + l15;
            af[m] = *(const bf16x8*)((const char*)qs + row * 128 + ((g * 16 + kk * 64) ^ swz));
        }
        #pragma unroll
        for (int n = 0; n < 8; ++n) {
            const int row = (w * 8 + n) * 16 + l15;
            const bf16x8 bfr = *(const bf16x8*)((const char*)ks + row * 128 + ((g * 16 + kk * 64) ^ swz));
            #pragma unroll
            for (int m = 0; m < 4; ++m)
                acc[m][n] = __builtin_amdgcn_mfma_f32_16x16x32_bf16(af[m], bfr, acc[m][n], 0, 0, 0);
        }
    }

    float rmax[4][4];
    #pragma unroll
    for (int m = 0; m < 4; ++m)
        #pragma unroll
        for (int i = 0; i < 4; ++i) {
            float mx = acc[m][0][i];
            #pragma unroll
            for (int n = 1; n < 8; ++n) mx = fmaxf(mx, acc[m][n][i]);
            mx = fmaxf(mx, __shfl_xor(mx, 1));
            mx = fmaxf(mx, __shfl_xor(mx, 2));
            mx = fmaxf(mx, __shfl_xor(mx, 4));
            mx = fmaxf(mx, __shfl_xor(mx, 8));
            if (l15 == 0) smax[w][m * 16 + g * 4 + i] = mx;
        }
    __syncthreads();
    #pragma unroll
    for (int m = 0; m < 4; ++m)
        #pragma unroll
        for (int i = 0; i < 4; ++i) {
            const int r = m * 16 + g * 4 + i;
            rmax[m][i] = fmaxf(fmaxf(smax[0][r], smax[1][r]),
                               fmaxf(smax[2][r], smax[3][r]));
        }
    float rinv[4][4];
    #pragma unroll
    for (int m = 0; m < 4; ++m)
        #pragma unroll
        for (int i = 0; i < 4; ++i) {
            float s = 0.f;
            #pragma unroll
            for (int n = 0; n < 8; ++n) {
                acc[m][n][i] = __expf(acc[m][n][i] - rmax[m][i]);
                s += acc[m][n][i];
            }
            s += __shfl_xor(s, 1); s += __shfl_xor(s, 2);
            s += __shfl_xor(s, 4); s += __shfl_xor(s, 8);
            if (l15 == 0) ssum[w][m * 16 + g * 4 + i] = s;
        }
    __syncthreads();
    #pragma unroll
    for (int m = 0; m < 4; ++m)
        #pragma unroll
        for (int i = 0; i < 4; ++i) {
            const int r = m * 16 + g * 4 + i;
            rinv[m][i] = 1.0f / (ssum[0][r] + ssum[1][r] + ssum[2][r] + ssum[3][r]);
        }

    u16* Pb = P + (hb * LLEN + qt * 64) * LLEN + w * 128;
    float cs[8];
    #pragma unroll
    for (int n = 0; n < 8; ++n) cs[n] = 0.f;
    #pragma unroll
    for (int m = 0; m < 4; ++m)
        #pragma unroll
        for (int i = 0; i < 4; ++i) {
            const int r = m * 16 + g * 4 + i;
            u16* pr = Pb + (long)r * LLEN + l15;
            const float iv = rinv[m][i];
            #pragma unroll
            for (int n = 0; n < 8; ++n) {
                const float p = acc[m][n][i] * iv;
                pr[n * 16] = f2bf(p);
                cs[n] += p;
            }
        }
    #pragma unroll
    for (int n = 0; n < 8; ++n) {
        cs[n] += __shfl_xor(cs[n], 16);
        cs[n] += __shfl_xor(cs[n], 32);
    }
    if (lane < 16) {
        float* cb = colsum + hb * 512 + w * 128 + lane;
        #pragma unroll
        for (int n = 0; n < 8; ++n) atomicAdd(&cb[n * 16], cs[n]);
    }
}

// Fused: preLN = o + hff @ W2^T + b2, then LayerNorm over D=512 and
// transpose-scatter to d_out[l][b][h*D+d] fp32. Block = 32 tokens x head h.
// K=64 single step; W2[h] (64 KB) staged whole into LDS.
// NOTE: token ordering within a head is tok = b*512 + l (inherited from
// P's [H][B][L][.] layout through K5/K6/K7) -> b = tok>>9, l = tok&511.
__global__ __launch_bounds__(256) void ffn2_ln(
    const u16* __restrict__ hff, const u16* __restrict__ W2bf,
    const float* __restrict__ b2, const u16* __restrict__ o,
    const float* __restrict__ lng, const float* __restrict__ lnb,
    float* __restrict__ out)
{
    __shared__ u16 W2s[512 * 64];   // 64 KB
    __shared__ u16 hs[32 * 64];     // 4 KB
    __shared__ float redS[4][32];
    __shared__ float redQ[4][32];

    const int h = blockIdx.z;
    const int m0 = blockIdx.x * 32;
    const int t = threadIdx.x;
    const int lane = t & 63, w = t >> 6;
    const int l15 = lane & 15, g = lane >> 4;
    const int wb = (t & 192) * 16;

    const char* w2g = (const char*)W2bf + (long)h * 65536;
    #pragma unroll
    for (int c = 0; c < 16; ++c)
        gload16(w2g + c * 4096 + t * 16, (char*)W2s + c * 4096 + wb);
    gload16((const char*)hff + ((long)h * NTOK + m0) * 128 + t * 16, (char*)hs + wb);
    __syncthreads();

    f32x4 acc[2][8];
    #pragma unroll
    for (int m = 0; m < 2; ++m)
        #pragma unroll
        for (int n = 0; n < 8; ++n)
            #pragma unroll
            for (int i = 0; i < 4; ++i) acc[m][n][i] = 0.f;

    #pragma unroll
    for (int kk = 0; kk < 2; ++kk) {
        bf16x8 af[2];
        #pragma unroll
        for (int m = 0; m < 2; ++m)
            af[m] = *(const bf16x8*)((const char*)hs + (m * 16 + l15) * 128 + kk * 64 + g * 16);
        #pragma unroll
        for (int n = 0; n < 8; ++n) {
            const int e = w * 128 + n * 16 + l15;
            const bf16x8 bfr = *(const bf16x8*)((const char*)W2s + e * 128 + kk * 64 + g * 16);
            #pragma unroll
            for (int m = 0; m < 2; ++m)
                acc[m][n] = __builtin_amdgcn_mfma_f32_16x16x32_bf16(af[m], bfr, acc[m][n], 0, 0, 0);
        }
    }

    // bias + residual, per-wave partial LN sums
    float b2v[8], gv[8], bv[8];
    #pragma unroll
    for (int n = 0; n < 8; ++n) {
        const int c = w * 128 + n * 16 + l15;
        b2v[n] = b2[h * DDIM + c];
        gv[n] = lng[h * DDIM + c];
        bv[n] = lnb[h * DDIM + c];
    }
    const u16* ob = o + ((long)h * NTOK + m0) * DDIM;
    #pragma unroll
    for (int m = 0; m < 2; ++m)
        #pragma unroll
        for (int i = 0; i < 4; ++i) {
            const int row = m * 16 + g * 4 + i;
            float s = 0.f, q = 0.f;
            #pragma unroll
            for (int n = 0; n < 8; ++n) {
                const int c = w * 128 + n * 16 + l15;
                const float v = acc[m][n][i] + b2v[n] + bf2f(ob[(long)row * DDIM + c]);
                acc[m][n][i] = v;
                s += v; q += v * v;
            }
            s += __shfl_xor(s, 1); q += __shfl_xor(q, 1);
            s += __shfl_xor(s, 2); q += __shfl_xor(q, 2);
            s += __shfl_xor(s, 4); q += __shfl_xor(q, 4);
            s += __shfl_xor(s, 8); q += __shfl_xor(q, 8);
            if (l15 == 0) { redS[w][row] = s; redQ[w][row] = q; }
        }
    __syncthreads();

    #pragma unroll
    for (int m = 0; m < 2; ++m)
        #pragma unroll
        for (int i = 0; i < 4; ++i) {
            const int row = m * 16 + g * 4 + i;
            const float s = redS[0][row] + redS[1][row] + redS[2][row] + redS[3][row];
            const float q = redQ[0][row] + redQ[1][row] + redQ[2][row] + redQ[3][row];
            const float mu = s * (1.0f / 512.0f);
            const float var = q * (1.0f / 512.0f) - mu * mu;
            const float rs = rsqrtf(var + 1e-5f);
            const int tok = m0 + row;
            const int b = tok >> 9, l = tok & 511;   // tok = b*512 + l
            float* op = out + ((long)(l * BBATCH + b)) * (HH * DDIM) + h * DDIM;
            #pragma unroll
            for (int n = 0; n < 8; ++n) {
                const int c = w * 128 + n * 16 + l15;
                op[c] = (acc[m][n][i] - mu) * rs * gv[n] + bv[n];
            }
        }
}

extern "C" void kernel_launch(void* const* d_in, const int* in_sizes, int n_in,
                              void* d_out, int out_size, void* d_ws, size_t ws_size,
                              hipStream_t stream) {
    const float* query = (const float*)d_in[0];
    const float* key   = (const float*)d_in[1];
    const float* value = (const float*)d_in[2];
    const float* WK = (const float*)d_in[3];
    const float* WQ = (const float*)d_in[4];
    const float* WV = (const float*)d_in[5];
    const float* Wt = (const float*)d_in[6];
    const float* W1 = (const float*)d_in[7];
    const float* b1 = (const float*)d_in[8];
    const float* W2 = (const float*)d_in[9];
    const float* b2 = (const float*)d_in[10];
    const float* lng = (const float*)d_in[11];
    const float* lnb = (const float*)d_in[12];

    // ---- workspace layout (bytes), peak 319,291,392 ----
    char* ws = (char*)d_ws;
    // [0, 128MB): kbf/WQbf/WKbf until K1; P from K3
    u16* kbf  = (u16*)(ws);                    // 16 MB
    u16* WQbf = (u16*)(ws + 16777216);         // 0.5 MB
    u16* WKbf = (u16*)(ws + 17301504);         // 0.5 MB
    u16* P    = (u16*)(ws);                    // 128 MB
    // [128MB, 256MB): vbf/WVbf until K2; o from K6
    u16* vbf  = (u16*)(ws + 134217728);        // 16 MB
    u16* WVbf = (u16*)(ws + 150994944);        // 0.5 MB
    u16* o    = (u16*)(ws + 134217728);        // 128 MB
    float* colsum = (float*)(ws + 268435456);  // 0.5 MB
    u16* qbf  = (u16*)(ws + 268959744);        // 16 MB, dead after K5
    u16* hff  = qbf;                           // 16 MB, produced at K7
    // [285736960, 319291392): wq/wk until K3; then Wt/W1/W2 bf16
    u16* wq   = (u16*)(ws + 285736960);
    u16* wk   = (u16*)(ws + 302514176);
    u16* Wtbf = (u16*)(ws + 285736960);        // 4 MB
    u16* W1bf = (u16*)(ws + 289931264);        // 0.5 MB
    u16* W2bf = (u16*)(ws + 290455552);        // 0.5 MB
    // d_out doubles as scratch until ffn2_ln overwrites all of it:
    u16* qmo = (u16*)d_out;                        // [H][B][L][D]
    u16* wvT = (u16*)((char*)d_out + 134217728);   // [H][B][D][L]

    if (ws_size < 319291392u) return;

    hipMemsetAsync(colsum, 0, 524288, stream);
    const dim3 blk(256);

    // fp32 -> bf16 conversions
    f2bf4<<<dim3(8192), blk, 0, stream>>>(query, qbf, 2097152);
    f2bf4<<<dim3(8192), blk, 0, stream>>>(key,   kbf, 2097152);
    f2bf4<<<dim3(8192), blk, 0, stream>>>(value, vbf, 2097152);
    f2bf4<<<dim3(256),  blk, 0, stream>>>(WQ, WQbf, 65536);
    f2bf4<<<dim3(256),  blk, 0, stream>>>(WK, WKbf, 65536);
    f2bf4<<<dim3(2048), blk, 0, stream>>>(WV, WVbf, 524288);

    // K1: wq/wk = l2norm(query/key @ WQ/WK^T) -> [H,B,L,K] bf16 (swizzled rows)
    mgemm<128, 128, M_WQK, 0, 1><<<dim3(4, 128, 1), blk, 0, stream>>>(
        qbf, WQbf, wq, 512, 512, 512, 0,
        0, 0, 0, 0, 0, 0, 1, nullptr, 0, nullptr, 0, 0, 0);
    mgemm<128, 128, M_WQK, 0, 1><<<dim3(4, 128, 1), blk, 0, stream>>>(
        kbf, WKbf, wk, 512, 512, 512, 0,
        0, 0, 0, 0, 0, 0, 1, nullptr, 0, nullptr, 0, 0, 0);

    // K3: MFMA softmax(QK^T) -> P, column sums -> colsum
    attn_mfma<<<dim3(8, 32, 8), blk, 0, stream>>>(wq, wk, P, colsum);

    // weight conversions into the now-dead wq/wk region
    f2bf4<<<dim3(2048), blk, 0, stream>>>(Wt, Wtbf, 524288);
    f2bf4<<<dim3(256),  blk, 0, stream>>>(W1, W1bf, 65536);
    f2bf4<<<dim3(256),  blk, 0, stream>>>(W2, W2bf, 65536);

    // K2: wvT[h,b,e,l] = (sum_d WV[h,e,d]*value[l,b,d]) / (1e-9+colsum[h,b,l])
    mgemm<128, 128, M_SCALECOL, 2, 0><<<dim3(4, 4, 256), blk, 0, stream>>>(
        WVbf, vbf, wvT, 512, 512, BBATCH * DDIM, 512,
        (long)DDIM * DDIM, 0, 0, DDIM,
        (long)BBATCH * DDIM * LLEN, (long)DDIM * LLEN, 32,
        nullptr, 0, colsum, (long)BBATCH * 512, 512, 0);

    // K5: qmo = query - P @ wvT^T   (b-major: aux rows L2-reused across h)
    mgemm<128, 128, M_SUBAUX, 1, 0><<<dim3(4, 4, 256), blk, 0, stream>>>(
        P, wvT, qmo, 512, 512, 512, 512,
        (long)BBATCH * LLEN * LLEN, (long)LLEN * LLEN,
        (long)BBATCH * DDIM * LLEN, (long)DDIM * LLEN,
        (long)BBATCH * LLEN * DDIM, (long)LLEN * DDIM, 32,
        nullptr, 0, qbf, 0, DDIM, BBATCH * DDIM);

    // K6: o = relu(qmo @ Wt^T)   (SWAPXY: qmo fetched ~once, Wt L2-resident)
    mgemm<128, 128, M_RELU, 0, 1><<<dim3(4, 128, 8), blk, 0, stream>>>(
        qmo, Wtbf, o, 512, 512, 512, 512,
        (long)NTOK * DDIM, 0, (long)DDIM * DDIM, 0,
        (long)NTOK * DDIM, 0, 1, nullptr, 512, nullptr, 0, 0, 0);

    // K7: hff = relu(o @ W1^T + b1)   (BN=64)
    mgemm<128, 64, M_RELU, 0, 0><<<dim3(128, 1, 8), blk, 0, stream>>>(
        o, W1bf, hff, 512, 512, 512, 64,
        (long)NTOK * DDIM, 0, (long)FFD * DDIM, 0,
        (long)NTOK * FFD, 0, 1, b1, 64, nullptr, 0, 0, 0);

    // K8 + LN + transpose fused: d_out = LN(o + hff@W2^T + b2) scattered fp32
    ffn2_ln<<<dim3(512, 1, 8), blk, 0, stream>>>(hff, W2bf, b2, o, lng, lnb,
                                                 (float*)d_out);
}